// Round 6
// baseline (94528.821 us; speedup 1.0000x reference)
//
#include <hip/hip_runtime.h>
#include <hip/hip_bf16.h>
#include <math.h>

// ---------------------------------------------------------------------------
// SpatialTransformerEncoder — round 6: r5 simple kernel + FP32 OUTPUT.
// (r3/r4/r5 produced identical, plausibly-correct values but encoded the
// output as bf16; the harness reads the reference's output dtype = float32.)
// One workgroup (1024 threads) per sample; serial scalar K-loops; syncs
// between all stages. fp32/bf16 input probe on ln1_s retained.
// ---------------------------------------------------------------------------

#define NB   2048
#define NC   3
#define NN   32
#define NE   256
#define NH   8
#define HD_  32
#define NL   3
#define NMLP 1024
#define NP   256
#define NK   17
#define NS   (NB*NC)
#define NT   1024      // threads per block

typedef unsigned short u16;

struct Params {
  const void* x; const void* mask;
  const void* kp_w; const void* kp_b;
  const void* view_tokens; const void* view_pos;
  const void* ln1_s; const void* ln1_b;
  const void* qkv_w; const void* qkv_b;
  const void* ap_w; const void* ap_b;
  const void* ln2_s; const void* ln2_b;
  const void* fc1_w; const void* fc1_b;
  const void* fc2_w; const void* fc2_b;
  const void* pool_probe;
  const void* pool_ln1_s; const void* pool_ln1_b;
  const void* pool_q_w; const void* pool_q_b;
  const void* pool_kv_w; const void* pool_kv_b;
  const void* pool_ap_w; const void* pool_ap_b;
  const void* pool_ln2_s; const void* pool_ln2_b;
  const void* pool_fc1_w; const void* pool_fc1_b;
  const void* pool_fc2_w; const void* pool_fc2_b;
  const void* pool_out_w; const void* pool_out_b;
  const void* last_s; const void* last_b;
  float* out;                      // FP32 output (reference returns float32)
};

__device__ __forceinline__ float b2f(u16 u) {
  return __uint_as_float(((unsigned)u) << 16);
}
__device__ __forceinline__ float geluf(float v) {
  return 0.5f * v * (1.0f + erff(v * 0.70710678118654752f));
}
template <bool BF>
__device__ __forceinline__ float LD(const void* q, int i) {
  if constexpr (BF) return b2f(((const u16*)q)[i]);
  else return ((const float*)q)[i];
}

struct Smem {
  float X[NK][NE];       // residual stream
  float Nn[NK][NE];      // LN output / attention context
  float Y[NK][NE];       // post-attn residual
  float U[NK][NMLP];     // QKV (768) / MLP hidden (1024) / pool KV (512)
  float S[NH][NK][NK];   // attention scores/probs
  float mu[NK], rs[NK];  // LN stats per row
  float Q[NE];           // pool q / normalized-y row
  float O[NE];           // pool attn-out / pre-LN out row
  float RowA[NE];        // pool y / y2 row
  float H1[NMLP];        // pool MLP hidden
  float Ps[NH][NK];      // pool attn probs
  int   Idx[NK];
};

template <bool BF>
__device__ void body(const Params& p, Smem& sm) {
  const int s   = blockIdx.x;
  const int c   = s % NC;
  const int tid = threadIdx.x;
  const size_t EB = BF ? 2 : 4;

  // ---- S0: visibility gather (layout probe verified in r3/r4) ----
  if (tid == 0) {
    const unsigned int* mw = (const unsigned int*)p.mask;
    bool byte_layout = false;
    for (int i = 0; i < 8; ++i) {
      const unsigned int w = mw[i];
      if (w != 0u && w != 1u && w != 0x3F800000u) { byte_layout = true; break; }
    }
    int np_ = 0;
    sm.Idx[np_++] = -1; // view token first
    if (byte_layout) {
      const unsigned char* mb = (const unsigned char*)p.mask;
      for (int n = 0; n < NN && np_ < NK; ++n)
        if (mb[(size_t)s * NN + n]) sm.Idx[np_++] = n;
    } else {
      for (int n = 0; n < NN && np_ < NK; ++n)
        if (mw[(size_t)s * NN + n] != 0u) sm.Idx[np_++] = n;
    }
    while (np_ < NK) sm.Idx[np_++] = 0;
  }
  __syncthreads();

  // ---- S1: embedding ----
  for (int idx = tid; idx < NK * NE; idx += NT) {
    const int t = idx >> 8, e = idx & 255;
    const int n = sm.Idx[t];
    float v;
    if (n < 0) {
      v = LD<BF>(p.view_tokens, c * NE + e) + LD<BF>(p.view_pos, c * NE + e);
    } else {
      const float x0 = LD<BF>(p.x, (s * NN + n) * 2 + 0);
      const float x1 = LD<BF>(p.x, (s * NN + n) * 2 + 1);
      const int   i2 = e & ~1;
      const float freq = expf(-((float)i2 / (float)NE) * logf(10000.0f));
      const float ang  = (float)n * freq;
      const float pe   = (e & 1) ? cosf(ang) : sinf(ang);
      v = x0 * LD<BF>(p.kp_w, e) + x1 * LD<BF>(p.kp_w, NE + e)
        + LD<BF>(p.kp_b, e) + pe;
    }
    sm.X[t][e] = v;
  }
  __syncthreads();

  // ---- transformer blocks ----
  for (int l = 0; l < NL; ++l) {
    const void* ln1s = (const char*)p.ln1_s + (size_t)l * NE * EB;
    const void* ln1b = (const char*)p.ln1_b + (size_t)l * NE * EB;
    const void* qkvw = (const char*)p.qkv_w + (size_t)l * NE * 3 * NE * EB;
    const void* qkvb = (const char*)p.qkv_b + (size_t)l * 3 * NE * EB;
    const void* apw  = (const char*)p.ap_w  + (size_t)l * NE * NE * EB;
    const void* apb  = (const char*)p.ap_b  + (size_t)l * NE * EB;
    const void* ln2s = (const char*)p.ln2_s + (size_t)l * NE * EB;
    const void* ln2b = (const char*)p.ln2_b + (size_t)l * NE * EB;
    const void* f1w  = (const char*)p.fc1_w + (size_t)l * NE * NMLP * EB;
    const void* f1b  = (const char*)p.fc1_b + (size_t)l * NMLP * EB;
    const void* f2w  = (const char*)p.fc2_w + (size_t)l * NMLP * NE * EB;
    const void* f2b  = (const char*)p.fc2_b + (size_t)l * NE * EB;

    // L1: LN1 stats (one thread per row, serial)
    if (tid < NK) {
      float s1 = 0.f, s2 = 0.f;
      for (int k = 0; k < NE; ++k) { const float v = sm.X[tid][k]; s1 += v; s2 += v * v; }
      const float m = s1 * (1.0f / NE);
      sm.mu[tid] = m;
      sm.rs[tid] = rsqrtf(s2 * (1.0f / NE) - m * m + 1e-5f);
    }
    __syncthreads();
    // L2: apply LN1 -> Nn
    for (int idx = tid; idx < NK * NE; idx += NT) {
      const int t = idx >> 8, e = idx & 255;
      sm.Nn[t][e] = (sm.X[t][e] - sm.mu[t]) * sm.rs[t] * LD<BF>(ln1s, e) + LD<BF>(ln1b, e);
    }
    __syncthreads();
    // L3: QKV -> U[t][0:768]
    for (int idx = tid; idx < NK * 768; idx += NT) {
      const int t = idx / 768, j = idx - t * 768;
      float a = LD<BF>(qkvb, j);
      for (int k = 0; k < NE; ++k) a += sm.Nn[t][k] * LD<BF>(qkvw, k * 768 + j);
      sm.U[t][j] = a;
    }
    __syncthreads();
    // L4: scores -> S[h][t][u]
    for (int idx = tid; idx < NH * NK * NK; idx += NT) {
      const int h = idx / (NK * NK), r = idx - h * NK * NK, t = r / NK, u = r - t * NK;
      float d = 0.f;
      for (int i = 0; i < HD_; ++i) d += sm.U[t][h * HD_ + i] * sm.U[u][NE + h * HD_ + i];
      sm.S[h][t][u] = d * 0.17677669529663687f;
    }
    __syncthreads();
    // L5: softmax rows in place
    for (int idx = tid; idx < NH * NK; idx += NT) {
      const int h = idx / NK, t = idx - h * NK;
      float mx = -1e30f;
      for (int u = 0; u < NK; ++u) mx = fmaxf(mx, sm.S[h][t][u]);
      float den = 0.f;
      for (int u = 0; u < NK; ++u) { const float e_ = expf(sm.S[h][t][u] - mx); sm.S[h][t][u] = e_; den += e_; }
      const float inv = 1.0f / den;
      for (int u = 0; u < NK; ++u) sm.S[h][t][u] *= inv;
    }
    __syncthreads();
    // L6: context = S @ V -> Nn
    for (int idx = tid; idx < NK * NE; idx += NT) {
      const int t = idx >> 8, j = idx & 255, h = j >> 5, d = j & 31;
      float o = 0.f;
      for (int u = 0; u < NK; ++u) o += sm.S[h][t][u] * sm.U[u][2 * NE + h * HD_ + d];
      sm.Nn[t][j] = o;
    }
    __syncthreads();
    // L7: proj + residual -> Y
    for (int idx = tid; idx < NK * NE; idx += NT) {
      const int t = idx >> 8, j = idx & 255;
      float a = LD<BF>(apb, j);
      for (int k = 0; k < NE; ++k) a += sm.Nn[t][k] * LD<BF>(apw, k * NE + j);
      sm.Y[t][j] = sm.X[t][j] + a;
    }
    __syncthreads();
    // L8: LN2 stats on Y
    if (tid < NK) {
      float s1 = 0.f, s2 = 0.f;
      for (int k = 0; k < NE; ++k) { const float v = sm.Y[tid][k]; s1 += v; s2 += v * v; }
      const float m = s1 * (1.0f / NE);
      sm.mu[tid] = m;
      sm.rs[tid] = rsqrtf(s2 * (1.0f / NE) - m * m + 1e-5f);
    }
    __syncthreads();
    // L9: apply LN2 -> Nn
    for (int idx = tid; idx < NK * NE; idx += NT) {
      const int t = idx >> 8, e = idx & 255;
      sm.Nn[t][e] = (sm.Y[t][e] - sm.mu[t]) * sm.rs[t] * LD<BF>(ln2s, e) + LD<BF>(ln2b, e);
    }
    __syncthreads();
    // L10: FC1 + GELU -> U[t][0:1024]
    for (int idx = tid; idx < NK * NMLP; idx += NT) {
      const int t = idx >> 10, j = idx & 1023;
      float a = LD<BF>(f1b, j);
      for (int k = 0; k < NE; ++k) a += sm.Nn[t][k] * LD<BF>(f1w, k * NMLP + j);
      sm.U[t][j] = geluf(a);
    }
    __syncthreads();
    // L11: FC2 + residual -> X
    for (int idx = tid; idx < NK * NE; idx += NT) {
      const int t = idx >> 8, j = idx & 255;
      float a = LD<BF>(f2b, j);
      for (int k = 0; k < NMLP; ++k) a += sm.U[t][k] * LD<BF>(f2w, k * NE + j);
      sm.X[t][j] = sm.Y[t][j] + a;
    }
    __syncthreads();
  }

  // ---- attention pooling ----
  // P1: pool LN1 stats on X
  if (tid < NK) {
    float s1 = 0.f, s2 = 0.f;
    for (int k = 0; k < NE; ++k) { const float v = sm.X[tid][k]; s1 += v; s2 += v * v; }
    const float m = s1 * (1.0f / NE);
    sm.mu[tid] = m;
    sm.rs[tid] = rsqrtf(s2 * (1.0f / NE) - m * m + 1e-5f);
  }
  __syncthreads();
  // P2: apply -> Nn
  for (int idx = tid; idx < NK * NE; idx += NT) {
    const int t = idx >> 8, e = idx & 255;
    sm.Nn[t][e] = (sm.X[t][e] - sm.mu[t]) * sm.rs[t] * LD<BF>(p.pool_ln1_s, e) + LD<BF>(p.pool_ln1_b, e);
  }
  __syncthreads();
  // P3: q row = probe @ pool_q_w + b
  if (tid < NE) {
    float a = LD<BF>(p.pool_q_b, tid);
    for (int k = 0; k < NE; ++k) a += LD<BF>(p.pool_probe, k) * LD<BF>(p.pool_q_w, k * NE + tid);
    sm.Q[tid] = a;
  }
  // P4: kv -> U[t][0:512]
  for (int idx = tid; idx < NK * 512; idx += NT) {
    const int t = idx / 512, j = idx - t * 512;
    float a = LD<BF>(p.pool_kv_b, j);
    for (int k = 0; k < NE; ++k) a += sm.Nn[t][k] * LD<BF>(p.pool_kv_w, k * 512 + j);
    sm.U[t][j] = a;
  }
  __syncthreads();
  // P5: scores -> Ps (pre-softmax)
  if (tid < NH * NK) {
    const int h = tid / NK, u = tid - h * NK;
    float d = 0.f;
    for (int i = 0; i < HD_; ++i) d += sm.Q[h * HD_ + i] * sm.U[u][h * HD_ + i];
    sm.Ps[h][u] = d * 0.17677669529663687f;
  }
  __syncthreads();
  // P6: softmax per head
  if (tid < NH) {
    const int h = tid;
    float mx = -1e30f;
    for (int u = 0; u < NK; ++u) mx = fmaxf(mx, sm.Ps[h][u]);
    float den = 0.f;
    for (int u = 0; u < NK; ++u) { const float e_ = expf(sm.Ps[h][u] - mx); sm.Ps[h][u] = e_; den += e_; }
    const float inv = 1.0f / den;
    for (int u = 0; u < NK; ++u) sm.Ps[h][u] *= inv;
  }
  __syncthreads();
  // P7: o row
  if (tid < NE) {
    const int h = tid >> 5, d = tid & 31;
    float o = 0.f;
    for (int u = 0; u < NK; ++u) o += sm.Ps[h][u] * sm.U[u][NE + h * HD_ + d];
    sm.O[tid] = o;
  }
  __syncthreads();
  // P8: y = probe + o @ pool_ap_w + b -> RowA
  if (tid < NE) {
    float a = LD<BF>(p.pool_ap_b, tid);
    for (int k = 0; k < NE; ++k) a += sm.O[k] * LD<BF>(p.pool_ap_w, k * NE + tid);
    sm.RowA[tid] = LD<BF>(p.pool_probe, tid) + a;
  }
  __syncthreads();
  // P9: LN(y) stats (thread 0 serial)
  if (tid == 0) {
    float s1 = 0.f, s2 = 0.f;
    for (int k = 0; k < NE; ++k) { const float v = sm.RowA[k]; s1 += v; s2 += v * v; }
    const float m = s1 * (1.0f / NE);
    sm.mu[0] = m;
    sm.rs[0] = rsqrtf(s2 * (1.0f / NE) - m * m + 1e-5f);
  }
  __syncthreads();
  // P10: normalized y -> Q
  if (tid < NE) {
    sm.Q[tid] = (sm.RowA[tid] - sm.mu[0]) * sm.rs[0] * LD<BF>(p.pool_ln2_s, tid) + LD<BF>(p.pool_ln2_b, tid);
  }
  __syncthreads();
  // P11: pool FC1 + GELU -> H1
  for (int idx = tid; idx < NMLP; idx += NT) {
    float a = LD<BF>(p.pool_fc1_b, idx);
    for (int k = 0; k < NE; ++k) a += sm.Q[k] * LD<BF>(p.pool_fc1_w, k * NMLP + idx);
    sm.H1[idx] = geluf(a);
  }
  __syncthreads();
  // P12: y2 = y + H1 @ pool_fc2_w + b  (in place on RowA)
  if (tid < NE) {
    float a = LD<BF>(p.pool_fc2_b, tid);
    for (int k = 0; k < NMLP; ++k) a += sm.H1[k] * LD<BF>(p.pool_fc2_w, k * NE + tid);
    sm.RowA[tid] += a;
  }
  __syncthreads();
  // P13: out_pre = y2 @ pool_out_w + b -> O
  if (tid < NP) {
    float a = LD<BF>(p.pool_out_b, tid);
    for (int k = 0; k < NE; ++k) a += sm.RowA[k] * LD<BF>(p.pool_out_w, k * NP + tid);
    sm.O[tid] = a;
  }
  __syncthreads();
  // P14: final LN stats (thread 0)
  if (tid == 0) {
    float s1 = 0.f, s2 = 0.f;
    for (int k = 0; k < NP; ++k) { const float v = sm.O[k]; s1 += v; s2 += v * v; }
    const float m = s1 * (1.0f / NP);
    sm.mu[0] = m;
    sm.rs[0] = rsqrtf(s2 * (1.0f / NP) - m * m + 1e-5f);
  }
  __syncthreads();
  // P15: write FP32 output (reference output dtype is float32)
  if (tid < NP) {
    const float res = (sm.O[tid] - sm.mu[0]) * sm.rs[0] * LD<BF>(p.last_s, tid) + LD<BF>(p.last_b, tid);
    p.out[(size_t)s * NP + tid] = res;
  }
}

__global__ __launch_bounds__(NT, 1)
void st_encoder_kernel(Params p) {
  __shared__ Smem sm;
  // ln1_s is all-ones: first u16 == 0x3F80 iff bf16; 0x0000 iff fp32 (LE).
  const bool isbf = (((const u16*)p.ln1_s)[0] == 0x3F80);
  if (isbf) body<true>(p, sm);
  else      body<false>(p, sm);
}

extern "C" void kernel_launch(void* const* d_in, const int* in_sizes, int n_in,
                              void* d_out, int out_size, void* d_ws, size_t ws_size,
                              hipStream_t stream) {
  (void)in_sizes; (void)n_in; (void)out_size; (void)d_ws; (void)ws_size;
  Params p;
  p.x           = d_in[0];
  p.mask        = d_in[1];
  p.kp_w        = d_in[2];
  p.kp_b        = d_in[3];
  p.view_tokens = d_in[4];
  p.view_pos    = d_in[5];
  p.ln1_s       = d_in[6];
  p.ln1_b       = d_in[7];
  p.qkv_w       = d_in[8];
  p.qkv_b       = d_in[9];
  p.ap_w        = d_in[10];
  p.ap_b        = d_in[11];
  p.ln2_s       = d_in[12];
  p.ln2_b       = d_in[13];
  p.fc1_w       = d_in[14];
  p.fc1_b       = d_in[15];
  p.fc2_w       = d_in[16];
  p.fc2_b       = d_in[17];
  p.pool_probe  = d_in[18];
  p.pool_ln1_s  = d_in[19];
  p.pool_ln1_b  = d_in[20];
  p.pool_q_w    = d_in[21];
  p.pool_q_b    = d_in[22];
  p.pool_kv_w   = d_in[23];
  p.pool_kv_b   = d_in[24];
  p.pool_ap_w   = d_in[25];
  p.pool_ap_b   = d_in[26];
  p.pool_ln2_s  = d_in[27];
  p.pool_ln2_b  = d_in[28];
  p.pool_fc1_w  = d_in[29];
  p.pool_fc1_b  = d_in[30];
  p.pool_fc2_w  = d_in[31];
  p.pool_fc2_b  = d_in[32];
  p.pool_out_w  = d_in[33];
  p.pool_out_b  = d_in[34];
  p.last_s      = d_in[35];
  p.last_b      = d_in[36];
  p.out         = (float*)d_out;
  st_encoder_kernel<<<dim3(NS), dim3(NT), 0, stream>>>(p);
}

// Round 7
// 27016.199 us; speedup vs baseline: 3.4990x; 3.4990x over previous
//
#include <hip/hip_runtime.h>
#include <hip/hip_bf16.h>
#include <math.h>

// ---------------------------------------------------------------------------
// SpatialTransformerEncoder — round 7: verified register-tiled kernel (r4
// math, bit-identical to the passing r5) + FP32 output. One 256-thread block
// per sample; GEMMs use wave-per-chunk column split with acc[17][4] register
// tiles, float4 LDS broadcast activations, float4 coalesced weight loads.
// ---------------------------------------------------------------------------

#define NB   2048
#define NC   3
#define NN   32
#define NE   256
#define NH   8
#define HDIM 32
#define NL   3
#define NMLP 1024
#define NP   256
#define NK   17        // 16 visible keypoints + view token
#define NS   (NB*NC)   // 6144

typedef unsigned short u16;

struct Params {
  const void* x; const void* mask;
  const void* kp_w; const void* kp_b;
  const void* view_tokens; const void* view_pos;
  const void* ln1_s; const void* ln1_b;
  const void* qkv_w; const void* qkv_b;
  const void* ap_w; const void* ap_b;
  const void* ln2_s; const void* ln2_b;
  const void* fc1_w; const void* fc1_b;
  const void* fc2_w; const void* fc2_b;
  const void* pool_probe;
  const void* pool_ln1_s; const void* pool_ln1_b;
  const void* pool_q_w; const void* pool_q_b;
  const void* pool_kv_w; const void* pool_kv_b;
  const void* pool_ap_w; const void* pool_ap_b;
  const void* pool_ln2_s; const void* pool_ln2_b;
  const void* pool_fc1_w; const void* pool_fc1_b;
  const void* pool_fc2_w; const void* pool_fc2_b;
  const void* pool_out_w; const void* pool_out_b;
  const void* last_s; const void* last_b;
  float* out;                      // FP32 output (reference returns float32)
};

__device__ __forceinline__ float b2f(u16 u) {
  return __uint_as_float(((unsigned)u) << 16);
}
__device__ __forceinline__ float geluf(float v) {
  return 0.5f * v * (1.0f + erff(v * 0.70710678118654752f)); // exact GELU
}

template <bool BF>
__device__ __forceinline__ float LD(const void* q, int i) {
  if constexpr (BF) return b2f(((const u16*)q)[i]);
  else return ((const float*)q)[i];
}
template <bool BF>
__device__ __forceinline__ float4 LD4(const void* q, int i) {
  if constexpr (BF) {
    const ushort4 u = *(const ushort4*)((const u16*)q + i);
    return make_float4(b2f(u.x), b2f(u.y), b2f(u.z), b2f(u.w));
  } else {
    return *(const float4*)((const float*)q + i);
  }
}

struct alignas(16) Smem {
  float X[NK][NE];     // residual stream
  float Y[NK][NE];     // post-attn residual
  float Nn[NK][NE];    // normalized / attention output
  float U[NK][NMLP];   // union: QKV(768) / MLP hidden(1024) / pool KV(512)
  float Q[NE];         // pool: q row / normalized y row
  float O[NE];         // pool: attention out row
  float RowA[NE];      // pool: y / y2 row
  float Hh[NMLP];      // pool: MLP hidden row
  float Pp[NH][NK];    // pool attention probs
  float Red[4];
  int   Idx[NK];
};

// ---- LayerNorm over 17 rows of 256, wave-per-row round robin ----
template <bool BF>
__device__ __forceinline__ void ln_rows(const float* __restrict__ In,
                                        float* __restrict__ Out,
                                        const void* __restrict__ gam,
                                        const void* __restrict__ bet) {
  const int lane = threadIdx.x & 63, w = threadIdx.x >> 6;
  for (int t = w; t < NK; t += 4) {
    const float* row = In + t * NE;
    float sum = 0.f, sq = 0.f;
#pragma unroll
    for (int kk = 0; kk < NE / 64; ++kk) {
      const float v = row[lane + 64 * kk];
      sum += v; sq += v * v;
    }
#pragma unroll
    for (int off = 32; off > 0; off >>= 1) {
      sum += __shfl_down(sum, off, 64);
      sq  += __shfl_down(sq,  off, 64);
    }
    sum = __shfl(sum, 0, 64);
    sq  = __shfl(sq,  0, 64);
    const float mu = sum * (1.0f / NE);
    const float r  = rsqrtf(sq * (1.0f / NE) - mu * mu + 1e-5f);
#pragma unroll
    for (int kk = 0; kk < NE / 64; ++kk) {
      const int k = lane + 64 * kk;
      Out[t * NE + k] = (row[k] - mu) * r * LD<BF>(gam, k) + LD<BF>(bet, k);
    }
  }
}

// ---- GEMM, wide N (multiple of 256): waves take disjoint 256-col chunks ----
template <bool BF, int KD, int EPI> // EPI: 0 none, 1 gelu
__device__ __forceinline__ void gemmD(const float* __restrict__ In, const int is,
                                      const void* __restrict__ W,
                                      const void* __restrict__ bias,
                                      const int Ncols,
                                      float* __restrict__ Out, const int os) {
  const int lane = threadIdx.x & 63, w = threadIdx.x >> 6;
  for (int ch = w; ch < (Ncols >> 8); ch += 4) {
    const int j0 = (ch << 8) + lane * 4;
    float acc[NK][4];
#pragma unroll
    for (int t = 0; t < NK; ++t) {
      acc[t][0] = 0.f; acc[t][1] = 0.f; acc[t][2] = 0.f; acc[t][3] = 0.f;
    }
    for (int k = 0; k < KD; k += 4) {
      float4 wf[4];
#pragma unroll
      for (int r = 0; r < 4; ++r) wf[r] = LD4<BF>(W, (k + r) * Ncols + j0);
#pragma unroll
      for (int t = 0; t < NK; ++t) {
        const float4 a = *(const float4*)(In + t * is + k);
        acc[t][0] += a.x * wf[0].x + a.y * wf[1].x + a.z * wf[2].x + a.w * wf[3].x;
        acc[t][1] += a.x * wf[0].y + a.y * wf[1].y + a.z * wf[2].y + a.w * wf[3].y;
        acc[t][2] += a.x * wf[0].z + a.y * wf[1].z + a.z * wf[2].z + a.w * wf[3].z;
        acc[t][3] += a.x * wf[0].w + a.y * wf[1].w + a.z * wf[2].w + a.w * wf[3].w;
      }
    }
    const float4 bb = LD4<BF>(bias, j0);
#pragma unroll
    for (int t = 0; t < NK; ++t) {
      float v0 = acc[t][0] + bb.x, v1 = acc[t][1] + bb.y;
      float v2 = acc[t][2] + bb.z, v3 = acc[t][3] + bb.w;
      if (EPI == 1) { v0 = geluf(v0); v1 = geluf(v1); v2 = geluf(v2); v3 = geluf(v3); }
      Out[t * os + j0 + 0] = v0; Out[t * os + j0 + 1] = v1;
      Out[t * os + j0 + 2] = v2; Out[t * os + j0 + 3] = v3;
    }
  }
}

// ---- GEMM, N = 256: rows split across waves, optional residual add ----
template <bool BF, int KD, bool RES>
__device__ __forceinline__ void gemmA(const float* __restrict__ In, const int is,
                                      const void* __restrict__ W,
                                      const void* __restrict__ bias,
                                      float* __restrict__ Out, const int os,
                                      const float* __restrict__ Resid, const int rs) {
  const int lane = threadIdx.x & 63, w = threadIdx.x >> 6;
  const int j0 = lane * 4;
  float acc[5][4];
#pragma unroll
  for (int i = 0; i < 5; ++i) {
    acc[i][0] = 0.f; acc[i][1] = 0.f; acc[i][2] = 0.f; acc[i][3] = 0.f;
  }
  for (int k = 0; k < KD; k += 4) {
    float4 wf[4];
#pragma unroll
    for (int r = 0; r < 4; ++r) wf[r] = LD4<BF>(W, (k + r) * NE + j0);
#pragma unroll
    for (int i = 0; i < 5; ++i) {
      const int t = w + 4 * i;
      if (t < NK) {
        const float4 a = *(const float4*)(In + t * is + k);
        acc[i][0] += a.x * wf[0].x + a.y * wf[1].x + a.z * wf[2].x + a.w * wf[3].x;
        acc[i][1] += a.x * wf[0].y + a.y * wf[1].y + a.z * wf[2].y + a.w * wf[3].y;
        acc[i][2] += a.x * wf[0].z + a.y * wf[1].z + a.z * wf[2].z + a.w * wf[3].z;
        acc[i][3] += a.x * wf[0].w + a.y * wf[1].w + a.z * wf[2].w + a.w * wf[3].w;
      }
    }
  }
  const float4 bb = LD4<BF>(bias, j0);
#pragma unroll
  for (int i = 0; i < 5; ++i) {
    const int t = w + 4 * i;
    if (t < NK) {
      float v0 = acc[i][0] + bb.x, v1 = acc[i][1] + bb.y;
      float v2 = acc[i][2] + bb.z, v3 = acc[i][3] + bb.w;
      if (RES) {
        v0 += Resid[t * rs + j0 + 0]; v1 += Resid[t * rs + j0 + 1];
        v2 += Resid[t * rs + j0 + 2]; v3 += Resid[t * rs + j0 + 3];
      }
      Out[t * os + j0 + 0] = v0; Out[t * os + j0 + 1] = v1;
      Out[t * os + j0 + 2] = v2; Out[t * os + j0 + 3] = v3;
    }
  }
}

// ---- block-wide sum over 256 threads ----
__device__ __forceinline__ float block_sum(float v, float* sRed) {
#pragma unroll
  for (int off = 32; off > 0; off >>= 1) v += __shfl_down(v, off, 64);
  __syncthreads(); // protect sRed from previous use
  if ((threadIdx.x & 63) == 0) sRed[threadIdx.x >> 6] = v;
  __syncthreads();
  return sRed[0] + sRed[1] + sRed[2] + sRed[3];
}

template <bool BF>
__device__ void body(const Params& p, Smem& sm) {
  const int s   = blockIdx.x;
  const int c   = s % NC;
  const int tid = threadIdx.x;
  const size_t EB = BF ? 2 : 4;

  // ---- 1. visibility gather (layout probe verified r3-r6) ----
  if (tid == 0) {
    const unsigned int* mw = (const unsigned int*)p.mask;
    bool byte_layout = false;
    for (int i = 0; i < 8; ++i) {
      const unsigned int w = mw[i];
      if (w != 0u && w != 1u && w != 0x3F800000u) { byte_layout = true; break; }
    }
    int np_ = 0;
    sm.Idx[np_++] = -1; // view token first
    if (byte_layout) {
      const unsigned char* mb = (const unsigned char*)p.mask;
      for (int n = 0; n < NN && np_ < NK; ++n)
        if (mb[(size_t)s * NN + n]) sm.Idx[np_++] = n;
    } else {
      for (int n = 0; n < NN && np_ < NK; ++n)
        if (mw[(size_t)s * NN + n] != 0u) sm.Idx[np_++] = n;
    }
    while (np_ < NK) sm.Idx[np_++] = 0;
  }
  __syncthreads();

  // ---- 2. embedding ----
  {
    const int e = tid;
    const float kw0 = LD<BF>(p.kp_w, e);
    const float kw1 = LD<BF>(p.kp_w, NE + e);
    const float kb  = LD<BF>(p.kp_b, e);
    const int   i2  = e & ~1;
    const float freq = expf(-((float)i2 / (float)NE) * logf(10000.0f));
    const float vt = LD<BF>(p.view_tokens, c * NE + e) + LD<BF>(p.view_pos, c * NE + e);
    for (int t = 0; t < NK; ++t) {
      const int n = sm.Idx[t];
      float v;
      if (n < 0) {
        v = vt;
      } else {
        const float x0 = LD<BF>(p.x, (s * NN + n) * 2 + 0);
        const float x1 = LD<BF>(p.x, (s * NN + n) * 2 + 1);
        const float ang = (float)n * freq;
        const float pe  = (e & 1) ? cosf(ang) : sinf(ang);
        v = x0 * kw0 + x1 * kw1 + kb + pe;
      }
      sm.X[t][e] = v;
    }
  }
  __syncthreads();

  // ---- 3. transformer blocks ----
  for (int l = 0; l < NL; ++l) {
    ln_rows<BF>(&sm.X[0][0], &sm.Nn[0][0],
                (const void*)((const char*)p.ln1_s + (size_t)l * NE * EB),
                (const void*)((const char*)p.ln1_b + (size_t)l * NE * EB));
    __syncthreads();
    // QKV: sm.U[t][0:256]=q, [256:512]=k, [512:768]=v
    gemmD<BF, NE, 0>(&sm.Nn[0][0], NE,
                     (const char*)p.qkv_w + (size_t)l * NE * 3 * NE * EB,
                     (const char*)p.qkv_b + (size_t)l * 3 * NE * EB,
                     3 * NE, &sm.U[0][0], NMLP);
    __syncthreads();
    // attention: one thread per (head, query-token)
    if (tid < NH * NK) {
      const int h = tid / NK, t = tid % NK;
      const float* qr = &sm.U[t][h * HDIM];
      float sc[NK];
      float mx = -1e30f;
#pragma unroll
      for (int u = 0; u < NK; ++u) {
        const float* kr = &sm.U[u][NE + h * HDIM];
        float d = 0.f;
        for (int i = 0; i < HDIM; ++i) d += qr[i] * kr[i];
        d *= 0.17677669529663687f; // HD^-0.5
        sc[u] = d;
        mx = fmaxf(mx, d);
      }
      float den = 0.f;
#pragma unroll
      for (int u = 0; u < NK; ++u) { sc[u] = __expf(sc[u] - mx); den += sc[u]; }
      const float inv = 1.0f / den;
      for (int i = 0; i < HDIM; ++i) {
        float o = 0.f;
#pragma unroll
        for (int u = 0; u < NK; ++u) o += sc[u] * sm.U[u][2 * NE + h * HDIM + i];
        sm.Nn[t][h * HDIM + i] = o * inv;
      }
    }
    __syncthreads();
    // proj + residual: Y = X + attn @ ap_w + ap_b
    gemmA<BF, NE, true>(&sm.Nn[0][0], NE,
                        (const char*)p.ap_w + (size_t)l * NE * NE * EB,
                        (const char*)p.ap_b + (size_t)l * NE * EB,
                        &sm.Y[0][0], NE, &sm.X[0][0], NE);
    __syncthreads();
    ln_rows<BF>(&sm.Y[0][0], &sm.Nn[0][0],
                (const void*)((const char*)p.ln2_s + (size_t)l * NE * EB),
                (const void*)((const char*)p.ln2_b + (size_t)l * NE * EB));
    __syncthreads();
    // FC1 + GELU
    gemmD<BF, NE, 1>(&sm.Nn[0][0], NE,
                     (const char*)p.fc1_w + (size_t)l * NE * NMLP * EB,
                     (const char*)p.fc1_b + (size_t)l * NMLP * EB,
                     NMLP, &sm.U[0][0], NMLP);
    __syncthreads();
    // FC2 + residual: X = Y + h @ fc2_w + fc2_b
    gemmA<BF, NMLP, true>(&sm.U[0][0], NMLP,
                          (const char*)p.fc2_w + (size_t)l * NMLP * NE * EB,
                          (const char*)p.fc2_b + (size_t)l * NE * EB,
                          &sm.X[0][0], NE, &sm.Y[0][0], NE);
    __syncthreads();
  }

  // ---- 4. attention pooling ----
  ln_rows<BF>(&sm.X[0][0], &sm.Nn[0][0], p.pool_ln1_s, p.pool_ln1_b);
  __syncthreads();
  // q row from probe
  {
    const int j = tid;
    float a = LD<BF>(p.pool_q_b, j);
    for (int k = 0; k < NE; k += 4) {
      a += LD<BF>(p.pool_probe, k + 0) * LD<BF>(p.pool_q_w, (k + 0) * NE + j) +
           LD<BF>(p.pool_probe, k + 1) * LD<BF>(p.pool_q_w, (k + 1) * NE + j) +
           LD<BF>(p.pool_probe, k + 2) * LD<BF>(p.pool_q_w, (k + 2) * NE + j) +
           LD<BF>(p.pool_probe, k + 3) * LD<BF>(p.pool_q_w, (k + 3) * NE + j);
    }
    sm.Q[j] = a;
  }
  // kv: sm.U[t][0:256]=kk, [256:512]=vv
  gemmD<BF, NE, 0>(&sm.Nn[0][0], NE, p.pool_kv_w, p.pool_kv_b, 2 * NE,
                   &sm.U[0][0], NMLP);
  __syncthreads();
  // scores + softmax per head
  if (tid < NH) {
    const int h = tid;
    float sc[NK];
    float mx = -1e30f;
#pragma unroll
    for (int u = 0; u < NK; ++u) {
      float d = 0.f;
      for (int i = 0; i < HDIM; ++i) d += sm.Q[h * HDIM + i] * sm.U[u][h * HDIM + i];
      d *= 0.17677669529663687f;
      sc[u] = d;
      mx = fmaxf(mx, d);
    }
    float den = 0.f;
#pragma unroll
    for (int u = 0; u < NK; ++u) { sc[u] = __expf(sc[u] - mx); den += sc[u]; }
    const float inv = 1.0f / den;
#pragma unroll
    for (int u = 0; u < NK; ++u) sm.Pp[h][u] = sc[u] * inv;
  }
  __syncthreads();
  // o row: weighted sum of vv
  {
    const int j = tid, h = j >> 5, i = j & 31;
    float o = 0.f;
#pragma unroll
    for (int u = 0; u < NK; ++u) o += sm.Pp[h][u] * sm.U[u][NE + h * HDIM + i];
    sm.O[j] = o;
  }
  __syncthreads();
  // y = probe + o @ ap_w + ap_b
  float yv;
  {
    const int j = tid;
    float a = LD<BF>(p.pool_ap_b, j);
    for (int k = 0; k < NE; k += 4) {
      const float4 oo = *(const float4*)&sm.O[k];
      a += oo.x * LD<BF>(p.pool_ap_w, (k + 0) * NE + j) +
           oo.y * LD<BF>(p.pool_ap_w, (k + 1) * NE + j) +
           oo.z * LD<BF>(p.pool_ap_w, (k + 2) * NE + j) +
           oo.w * LD<BF>(p.pool_ap_w, (k + 3) * NE + j);
    }
    yv = LD<BF>(p.pool_probe, j) + a;
  }
  // LN(y) -> sm.Q
  {
    const float s1 = block_sum(yv, sm.Red);
    const float s2 = block_sum(yv * yv, sm.Red);
    const float mu = s1 * (1.0f / NE);
    const float r  = rsqrtf(s2 * (1.0f / NE) - mu * mu + 1e-5f);
    sm.Q[tid] = (yv - mu) * r * LD<BF>(p.pool_ln2_s, tid) + LD<BF>(p.pool_ln2_b, tid);
  }
  __syncthreads();
  // MLP hidden row
  {
    const int j = tid;
    float h1[4];
#pragma unroll
    for (int c4 = 0; c4 < 4; ++c4) h1[c4] = LD<BF>(p.pool_fc1_b, c4 * NE + j);
    for (int k = 0; k < NE; k += 4) {
      const float4 nq = *(const float4*)&sm.Q[k];
#pragma unroll
      for (int c4 = 0; c4 < 4; ++c4) {
        const int col = c4 * NE + j;
        h1[c4] += nq.x * LD<BF>(p.pool_fc1_w, (k + 0) * NMLP + col) +
                  nq.y * LD<BF>(p.pool_fc1_w, (k + 1) * NMLP + col) +
                  nq.z * LD<BF>(p.pool_fc1_w, (k + 2) * NMLP + col) +
                  nq.w * LD<BF>(p.pool_fc1_w, (k + 3) * NMLP + col);
      }
    }
#pragma unroll
    for (int c4 = 0; c4 < 4; ++c4) sm.Hh[c4 * NE + j] = geluf(h1[c4]);
  }
  __syncthreads();
  // y2 = y + h @ fc2 + b
  {
    const int j = tid;
    float a = LD<BF>(p.pool_fc2_b, j);
    for (int k = 0; k < NMLP; k += 4) {
      const float4 hh = *(const float4*)&sm.Hh[k];
      a += hh.x * LD<BF>(p.pool_fc2_w, (k + 0) * NE + j) +
           hh.y * LD<BF>(p.pool_fc2_w, (k + 1) * NE + j) +
           hh.z * LD<BF>(p.pool_fc2_w, (k + 2) * NE + j) +
           hh.w * LD<BF>(p.pool_fc2_w, (k + 3) * NE + j);
    }
    yv += a;
    sm.RowA[j] = yv;
  }
  __syncthreads();
  // out = y2 @ out_w + out_b ; final LN
  float ov;
  {
    const int j = tid;
    float a = LD<BF>(p.pool_out_b, j);
    for (int k = 0; k < NE; k += 4) {
      const float4 yy = *(const float4*)&sm.RowA[k];
      a += yy.x * LD<BF>(p.pool_out_w, (k + 0) * NP + j) +
           yy.y * LD<BF>(p.pool_out_w, (k + 1) * NP + j) +
           yy.z * LD<BF>(p.pool_out_w, (k + 2) * NP + j) +
           yy.w * LD<BF>(p.pool_out_w, (k + 3) * NP + j);
    }
    ov = a;
  }
  {
    const float s1 = block_sum(ov, sm.Red);
    const float s2 = block_sum(ov * ov, sm.Red);
    const float mu = s1 * (1.0f / NP);
    const float r  = rsqrtf(s2 * (1.0f / NP) - mu * mu + 1e-5f);
    const float res = (ov - mu) * r * LD<BF>(p.last_s, tid) + LD<BF>(p.last_b, tid);
    p.out[(size_t)s * NP + tid] = res;  // FP32 store
  }
}

__global__ __launch_bounds__(256, 1)
void st_encoder_kernel(Params p) {
  __shared__ Smem sm;
  // ln1_s is all-ones: first u16 == 0x3F80 iff bf16; 0x0000 iff fp32 (LE).
  const bool isbf = (((const u16*)p.ln1_s)[0] == 0x3F80);
  if (isbf) body<true>(p, sm);
  else      body<false>(p, sm);
}

extern "C" void kernel_launch(void* const* d_in, const int* in_sizes, int n_in,
                              void* d_out, int out_size, void* d_ws, size_t ws_size,
                              hipStream_t stream) {
  (void)in_sizes; (void)n_in; (void)out_size; (void)d_ws; (void)ws_size;
  Params p;
  p.x           = d_in[0];
  p.mask        = d_in[1];
  p.kp_w        = d_in[2];
  p.kp_b        = d_in[3];
  p.view_tokens = d_in[4];
  p.view_pos    = d_in[5];
  p.ln1_s       = d_in[6];
  p.ln1_b       = d_in[7];
  p.qkv_w       = d_in[8];
  p.qkv_b       = d_in[9];
  p.ap_w        = d_in[10];
  p.ap_b        = d_in[11];
  p.ln2_s       = d_in[12];
  p.ln2_b       = d_in[13];
  p.fc1_w       = d_in[14];
  p.fc1_b       = d_in[15];
  p.fc2_w       = d_in[16];
  p.fc2_b       = d_in[17];
  p.pool_probe  = d_in[18];
  p.pool_ln1_s  = d_in[19];
  p.pool_ln1_b  = d_in[20];
  p.pool_q_w    = d_in[21];
  p.pool_q_b    = d_in[22];
  p.pool_kv_w   = d_in[23];
  p.pool_kv_b   = d_in[24];
  p.pool_ap_w   = d_in[25];
  p.pool_ap_b   = d_in[26];
  p.pool_ln2_s  = d_in[27];
  p.pool_ln2_b  = d_in[28];
  p.pool_fc1_w  = d_in[29];
  p.pool_fc1_b  = d_in[30];
  p.pool_fc2_w  = d_in[31];
  p.pool_fc2_b  = d_in[32];
  p.pool_out_w  = d_in[33];
  p.pool_out_b  = d_in[34];
  p.last_s      = d_in[35];
  p.last_b      = d_in[36];
  p.out         = (float*)d_out;
  st_encoder_kernel<<<dim3(NS), dim3(256), 0, stream>>>(p);
}

// Round 8
// 16270.270 us; speedup vs baseline: 5.8099x; 1.6605x over previous
//
#include <hip/hip_runtime.h>
#include <hip/hip_bf16.h>
#include <math.h>

// ---------------------------------------------------------------------------
// SpatialTransformerEncoder — round 8: 1024-thread blocks (16 waves/CU, 50%
// occupancy) with generalized wave partitioning. Math is bit-identical to the
// passing r7 kernel (same per-output accumulation order); Y buffer eliminated
// (in-place residual adds). One block per sample, LDS ~112 KB -> 1 block/CU.
// ---------------------------------------------------------------------------

#define NB   2048
#define NC   3
#define NN   32
#define NE   256
#define NH   8
#define HDIM 32
#define NL   3
#define NMLP 1024
#define NP   256
#define NK   17        // 16 visible keypoints + view token
#define NS   (NB*NC)   // 6144
#define NT   1024      // threads per block (16 waves)
#define NW   16        // waves per block

typedef unsigned short u16;

struct Params {
  const void* x; const void* mask;
  const void* kp_w; const void* kp_b;
  const void* view_tokens; const void* view_pos;
  const void* ln1_s; const void* ln1_b;
  const void* qkv_w; const void* qkv_b;
  const void* ap_w; const void* ap_b;
  const void* ln2_s; const void* ln2_b;
  const void* fc1_w; const void* fc1_b;
  const void* fc2_w; const void* fc2_b;
  const void* pool_probe;
  const void* pool_ln1_s; const void* pool_ln1_b;
  const void* pool_q_w; const void* pool_q_b;
  const void* pool_kv_w; const void* pool_kv_b;
  const void* pool_ap_w; const void* pool_ap_b;
  const void* pool_ln2_s; const void* pool_ln2_b;
  const void* pool_fc1_w; const void* pool_fc1_b;
  const void* pool_fc2_w; const void* pool_fc2_b;
  const void* pool_out_w; const void* pool_out_b;
  const void* last_s; const void* last_b;
  float* out;                      // FP32 output
};

__device__ __forceinline__ float b2f(u16 u) {
  return __uint_as_float(((unsigned)u) << 16);
}
__device__ __forceinline__ float geluf(float v) {
  return 0.5f * v * (1.0f + erff(v * 0.70710678118654752f)); // exact GELU
}

template <bool BF>
__device__ __forceinline__ float LD(const void* q, int i) {
  if constexpr (BF) return b2f(((const u16*)q)[i]);
  else return ((const float*)q)[i];
}
// load CPL consecutive floats (CPL = 2 or 4), vectorized
template <bool BF, int CPL>
__device__ __forceinline__ void ldc(const void* q, int i, float* o) {
  if constexpr (CPL == 4) {
    if constexpr (BF) {
      const ushort4 u = *(const ushort4*)((const u16*)q + i);
      o[0] = b2f(u.x); o[1] = b2f(u.y); o[2] = b2f(u.z); o[3] = b2f(u.w);
    } else {
      const float4 v = *(const float4*)((const float*)q + i);
      o[0] = v.x; o[1] = v.y; o[2] = v.z; o[3] = v.w;
    }
  } else {
    if constexpr (BF) {
      const ushort2 u = *(const ushort2*)((const u16*)q + i);
      o[0] = b2f(u.x); o[1] = b2f(u.y);
    } else {
      const float2 v = *(const float2*)((const float*)q + i);
      o[0] = v.x; o[1] = v.y;
    }
  }
}

struct alignas(16) Smem {
  float X[NK][NE];     // residual stream (updated in place)
  float Nn[NK][NE];    // LN output / attention context
  float U[NK][NMLP];   // QKV (768) / MLP hidden (1024) / pool KV (512)
  float Q[NE];         // pool: q row / normalized-y row
  float O[NE];         // pool: attention-out row
  float RowA[NE];      // pool: y / y2 row
  float Hh[NMLP];      // pool: MLP hidden row
  float Pp[NH][NK];    // pool attention probs
  float Red[NW];
  int   Idx[NK];
};

// ---- LayerNorm over 17 rows of 256, wave-per-row (16 waves) ----
template <bool BF>
__device__ __forceinline__ void ln_rows(const float* __restrict__ In,
                                        float* __restrict__ Out,
                                        const void* __restrict__ gam,
                                        const void* __restrict__ bet) {
  const int lane = threadIdx.x & 63, w = threadIdx.x >> 6;
  for (int t = w; t < NK; t += NW) {
    const float* row = In + t * NE;
    float sum = 0.f, sq = 0.f;
#pragma unroll
    for (int kk = 0; kk < NE / 64; ++kk) {
      const float v = row[lane + 64 * kk];
      sum += v; sq += v * v;
    }
#pragma unroll
    for (int off = 32; off > 0; off >>= 1) {
      sum += __shfl_down(sum, off, 64);
      sq  += __shfl_down(sq,  off, 64);
    }
    sum = __shfl(sum, 0, 64);
    sq  = __shfl(sq,  0, 64);
    const float mu = sum * (1.0f / NE);
    const float r  = rsqrtf(sq * (1.0f / NE) - mu * mu + 1e-5f);
#pragma unroll
    for (int kk = 0; kk < NE / 64; ++kk) {
      const int k = lane + 64 * kk;
      Out[t * NE + k] = (row[k] - mu) * r * LD<BF>(gam, k) + LD<BF>(bet, k);
    }
  }
}

// ---- generic GEMM: cols in NCH chunks of 64*CPL, rows in RG groups of RPG.
//      wave w -> chunk (w % NCH), row group (w / NCH). EPI: 0 none, 1 gelu.
//      RES: Out[t][j] = (in-place) Out[t][j] + acc + bias. ----
template <bool BF, int KD, int EPI, int NCH, int CPL, int RG, int RPG, bool RES>
__device__ __forceinline__ void gemmW(const float* __restrict__ In, const int is,
                                      const void* __restrict__ W, const int ws,
                                      const void* __restrict__ bias,
                                      float* __restrict__ Out, const int os) {
  const int lane = threadIdx.x & 63, w = threadIdx.x >> 6;
  if (w >= NCH * RG) return;
  const int ch = w % NCH;
  const int t0 = (w / NCH) * RPG;
  if (t0 >= NK) return;
  const int nt = (NK - t0 < RPG) ? (NK - t0) : RPG;
  const int j0 = ch * (64 * CPL) + lane * CPL;
  float acc[RPG][CPL];
#pragma unroll
  for (int i = 0; i < RPG; ++i)
#pragma unroll
    for (int c = 0; c < CPL; ++c) acc[i][c] = 0.f;
  for (int k = 0; k < KD; k += 4) {
    float wf[4][CPL];
#pragma unroll
    for (int r = 0; r < 4; ++r) ldc<BF, CPL>(W, (k + r) * ws + j0, wf[r]);
#pragma unroll
    for (int i = 0; i < RPG; ++i) {
      if (i < nt) {
        const float4 a = *(const float4*)(In + (t0 + i) * is + k);
#pragma unroll
        for (int c = 0; c < CPL; ++c)
          acc[i][c] += a.x * wf[0][c] + a.y * wf[1][c] +
                       a.z * wf[2][c] + a.w * wf[3][c];
      }
    }
  }
  float bb[CPL];
  ldc<BF, CPL>(bias, j0, bb);
#pragma unroll
  for (int i = 0; i < RPG; ++i) {
    if (i < nt) {
#pragma unroll
      for (int c = 0; c < CPL; ++c) {
        float v = acc[i][c] + bb[c];
        if (EPI == 1) v = geluf(v);
        if (RES) v += Out[(t0 + i) * os + j0 + c];
        Out[(t0 + i) * os + j0 + c] = v;
      }
    }
  }
}

// ---- block-wide sum over 1024 threads ----
__device__ __forceinline__ float block_sum(float v, float* sRed) {
#pragma unroll
  for (int off = 32; off > 0; off >>= 1) v += __shfl_down(v, off, 64);
  __syncthreads(); // protect sRed from previous use
  if ((threadIdx.x & 63) == 0) sRed[threadIdx.x >> 6] = v;
  __syncthreads();
  float s = 0.f;
#pragma unroll
  for (int i = 0; i < NW; ++i) s += sRed[i];
  return s;
}

template <bool BF>
__device__ void body(const Params& p, Smem& sm) {
  const int s   = blockIdx.x;
  const int c   = s % NC;
  const int tid = threadIdx.x;
  const size_t EB = BF ? 2 : 4;

  // ---- 1. visibility gather (layout probe verified r3-r7) ----
  if (tid == 0) {
    const unsigned int* mw = (const unsigned int*)p.mask;
    bool byte_layout = false;
    for (int i = 0; i < 8; ++i) {
      const unsigned int w = mw[i];
      if (w != 0u && w != 1u && w != 0x3F800000u) { byte_layout = true; break; }
    }
    int np_ = 0;
    sm.Idx[np_++] = -1; // view token first
    if (byte_layout) {
      const unsigned char* mb = (const unsigned char*)p.mask;
      for (int n = 0; n < NN && np_ < NK; ++n)
        if (mb[(size_t)s * NN + n]) sm.Idx[np_++] = n;
    } else {
      for (int n = 0; n < NN && np_ < NK; ++n)
        if (mw[(size_t)s * NN + n] != 0u) sm.Idx[np_++] = n;
    }
    while (np_ < NK) sm.Idx[np_++] = 0;
  }
  __syncthreads();

  // ---- 2. embedding (4 thread-quarters handle t = q, q+4, ...) ----
  {
    const int e = tid & 255, q = tid >> 8;
    const float kw0 = LD<BF>(p.kp_w, e);
    const float kw1 = LD<BF>(p.kp_w, NE + e);
    const float kb  = LD<BF>(p.kp_b, e);
    const int   i2  = e & ~1;
    const float freq = expf(-((float)i2 / (float)NE) * logf(10000.0f));
    const float vt = LD<BF>(p.view_tokens, c * NE + e) + LD<BF>(p.view_pos, c * NE + e);
    for (int t = q; t < NK; t += 4) {
      const int n = sm.Idx[t];
      float v;
      if (n < 0) {
        v = vt;
      } else {
        const float x0 = LD<BF>(p.x, (s * NN + n) * 2 + 0);
        const float x1 = LD<BF>(p.x, (s * NN + n) * 2 + 1);
        const float ang = (float)n * freq;
        const float pe  = (e & 1) ? cosf(ang) : sinf(ang);
        v = x0 * kw0 + x1 * kw1 + kb + pe;
      }
      sm.X[t][e] = v;
    }
  }
  __syncthreads();

  // ---- 3. transformer blocks ----
  for (int l = 0; l < NL; ++l) {
    ln_rows<BF>(&sm.X[0][0], &sm.Nn[0][0],
                (const void*)((const char*)p.ln1_s + (size_t)l * NE * EB),
                (const void*)((const char*)p.ln1_b + (size_t)l * NE * EB));
    __syncthreads();
    // QKV (N=768): 3 chunks x 5 row groups (RPG=4)
    gemmW<BF, NE, 0, 3, 4, 5, 4, false>(
        &sm.Nn[0][0], NE,
        (const char*)p.qkv_w + (size_t)l * NE * 3 * NE * EB, 3 * NE,
        (const char*)p.qkv_b + (size_t)l * 3 * NE * EB,
        &sm.U[0][0], NMLP);
    __syncthreads();
    // attention: one thread per (head, query-token)
    if (tid < NH * NK) {
      const int h = tid / NK, t = tid % NK;
      const float* qr = &sm.U[t][h * HDIM];
      float sc[NK];
      float mx = -1e30f;
#pragma unroll
      for (int u = 0; u < NK; ++u) {
        const float* kr = &sm.U[u][NE + h * HDIM];
        float d = 0.f;
        for (int i = 0; i < HDIM; ++i) d += qr[i] * kr[i];
        d *= 0.17677669529663687f; // HD^-0.5
        sc[u] = d;
        mx = fmaxf(mx, d);
      }
      float den = 0.f;
#pragma unroll
      for (int u = 0; u < NK; ++u) { sc[u] = __expf(sc[u] - mx); den += sc[u]; }
      const float inv = 1.0f / den;
      for (int i = 0; i < HDIM; ++i) {
        float o = 0.f;
#pragma unroll
        for (int u = 0; u < NK; ++u) o += sc[u] * sm.U[u][2 * NE + h * HDIM + i];
        sm.Nn[t][h * HDIM + i] = o * inv;
      }
    }
    __syncthreads();
    // proj + residual in place: X += Nn @ ap_w + ap_b  (2 chunks x 8 rg, CPL=2)
    gemmW<BF, NE, 0, 2, 2, 8, 3, true>(
        &sm.Nn[0][0], NE,
        (const char*)p.ap_w + (size_t)l * NE * NE * EB, NE,
        (const char*)p.ap_b + (size_t)l * NE * EB,
        &sm.X[0][0], NE);
    __syncthreads();
    ln_rows<BF>(&sm.X[0][0], &sm.Nn[0][0],
                (const void*)((const char*)p.ln2_s + (size_t)l * NE * EB),
                (const void*)((const char*)p.ln2_b + (size_t)l * NE * EB));
    __syncthreads();
    // FC1 + GELU (N=1024): 4 chunks x 4 row groups (RPG=5)
    gemmW<BF, NE, 1, 4, 4, 4, 5, false>(
        &sm.Nn[0][0], NE,
        (const char*)p.fc1_w + (size_t)l * NE * NMLP * EB, NMLP,
        (const char*)p.fc1_b + (size_t)l * NMLP * EB,
        &sm.U[0][0], NMLP);
    __syncthreads();
    // FC2 + residual in place: X += U @ fc2_w + fc2_b
    gemmW<BF, NMLP, 0, 2, 2, 8, 3, true>(
        &sm.U[0][0], NMLP,
        (const char*)p.fc2_w + (size_t)l * NMLP * NE * EB, NE,
        (const char*)p.fc2_b + (size_t)l * NE * EB,
        &sm.X[0][0], NE);
    __syncthreads();
  }

  // ---- 4. attention pooling ----
  ln_rows<BF>(&sm.X[0][0], &sm.Nn[0][0], p.pool_ln1_s, p.pool_ln1_b);
  __syncthreads();
  // q row from probe (independent of Nn)
  if (tid < NE) {
    const int j = tid;
    float a = LD<BF>(p.pool_q_b, j);
    for (int k = 0; k < NE; k += 4) {
      a += LD<BF>(p.pool_probe, k + 0) * LD<BF>(p.pool_q_w, (k + 0) * NE + j) +
           LD<BF>(p.pool_probe, k + 1) * LD<BF>(p.pool_q_w, (k + 1) * NE + j) +
           LD<BF>(p.pool_probe, k + 2) * LD<BF>(p.pool_q_w, (k + 2) * NE + j) +
           LD<BF>(p.pool_probe, k + 3) * LD<BF>(p.pool_q_w, (k + 3) * NE + j);
    }
    sm.Q[j] = a;
  }
  // kv (N=512): 2 chunks x 8 row groups (RPG=3)
  gemmW<BF, NE, 0, 2, 4, 8, 3, false>(
      &sm.Nn[0][0], NE, p.pool_kv_w, 2 * NE, p.pool_kv_b, &sm.U[0][0], NMLP);
  __syncthreads();
  // scores + softmax per head
  if (tid < NH) {
    const int h = tid;
    float sc[NK];
    float mx = -1e30f;
#pragma unroll
    for (int u = 0; u < NK; ++u) {
      float d = 0.f;
      for (int i = 0; i < HDIM; ++i) d += sm.Q[h * HDIM + i] * sm.U[u][h * HDIM + i];
      d *= 0.17677669529663687f;
      sc[u] = d;
      mx = fmaxf(mx, d);
    }
    float den = 0.f;
#pragma unroll
    for (int u = 0; u < NK; ++u) { sc[u] = __expf(sc[u] - mx); den += sc[u]; }
    const float inv = 1.0f / den;
#pragma unroll
    for (int u = 0; u < NK; ++u) sm.Pp[h][u] = sc[u] * inv;
  }
  __syncthreads();
  // o row: weighted sum of vv
  if (tid < NE) {
    const int j = tid, h = j >> 5, i = j & 31;
    float o = 0.f;
#pragma unroll
    for (int u = 0; u < NK; ++u) o += sm.Pp[h][u] * sm.U[u][NE + h * HDIM + i];
    sm.O[j] = o;
  }
  __syncthreads();
  // y = probe + o @ ap_w + ap_b
  float yv = 0.f;
  if (tid < NE) {
    const int j = tid;
    float a = LD<BF>(p.pool_ap_b, j);
    for (int k = 0; k < NE; k += 4) {
      const float4 oo = *(const float4*)&sm.O[k];
      a += oo.x * LD<BF>(p.pool_ap_w, (k + 0) * NE + j) +
           oo.y * LD<BF>(p.pool_ap_w, (k + 1) * NE + j) +
           oo.z * LD<BF>(p.pool_ap_w, (k + 2) * NE + j) +
           oo.w * LD<BF>(p.pool_ap_w, (k + 3) * NE + j);
    }
    yv = LD<BF>(p.pool_probe, j) + a;
  }
  // LN(y) -> sm.Q
  {
    const float s1 = block_sum(yv, sm.Red);
    const float s2 = block_sum(yv * yv, sm.Red);
    const float mu = s1 * (1.0f / NE);
    const float r  = rsqrtf(s2 * (1.0f / NE) - mu * mu + 1e-5f);
    if (tid < NE)
      sm.Q[tid] = (yv - mu) * r * LD<BF>(p.pool_ln2_s, tid) + LD<BF>(p.pool_ln2_b, tid);
  }
  __syncthreads();
  // MLP hidden row (1024 outputs, 1 per thread)
  {
    const int j = tid;
    float a = LD<BF>(p.pool_fc1_b, j);
    for (int k = 0; k < NE; k += 4) {
      const float4 nq = *(const float4*)&sm.Q[k];
      a += nq.x * LD<BF>(p.pool_fc1_w, (k + 0) * NMLP + j) +
           nq.y * LD<BF>(p.pool_fc1_w, (k + 1) * NMLP + j) +
           nq.z * LD<BF>(p.pool_fc1_w, (k + 2) * NMLP + j) +
           nq.w * LD<BF>(p.pool_fc1_w, (k + 3) * NMLP + j);
    }
    sm.Hh[j] = geluf(a);
  }
  __syncthreads();
  // y2 = y + Hh @ fc2 + b -> RowA
  if (tid < NE) {
    const int j = tid;
    float a = LD<BF>(p.pool_fc2_b, j);
    for (int k = 0; k < NMLP; k += 4) {
      const float4 hh = *(const float4*)&sm.Hh[k];
      a += hh.x * LD<BF>(p.pool_fc2_w, (k + 0) * NE + j) +
           hh.y * LD<BF>(p.pool_fc2_w, (k + 1) * NE + j) +
           hh.z * LD<BF>(p.pool_fc2_w, (k + 2) * NE + j) +
           hh.w * LD<BF>(p.pool_fc2_w, (k + 3) * NE + j);
    }
    sm.RowA[j] = yv + a;
  }
  __syncthreads();
  // out = y2 @ out_w + out_b ; final LN
  float ov = 0.f;
  if (tid < NP) {
    const int j = tid;
    float a = LD<BF>(p.pool_out_b, j);
    for (int k = 0; k < NE; k += 4) {
      const float4 yy = *(const float4*)&sm.RowA[k];
      a += yy.x * LD<BF>(p.pool_out_w, (k + 0) * NP + j) +
           yy.y * LD<BF>(p.pool_out_w, (k + 1) * NP + j) +
           yy.z * LD<BF>(p.pool_out_w, (k + 2) * NP + j) +
           yy.w * LD<BF>(p.pool_out_w, (k + 3) * NP + j);
    }
    ov = a;
  }
  {
    const float s1 = block_sum(ov, sm.Red);
    const float s2 = block_sum(ov * ov, sm.Red);
    const float mu = s1 * (1.0f / NP);
    const float r  = rsqrtf(s2 * (1.0f / NP) - mu * mu + 1e-5f);
    if (tid < NP) {
      const float res = (ov - mu) * r * LD<BF>(p.last_s, tid) + LD<BF>(p.last_b, tid);
      p.out[(size_t)s * NP + tid] = res;  // FP32 store
    }
  }
}

__global__ __launch_bounds__(NT, 1)
void st_encoder_kernel(Params p) {
  __shared__ Smem sm;
  // ln1_s is all-ones: first u16 == 0x3F80 iff bf16; 0x0000 iff fp32 (LE).
  const bool isbf = (((const u16*)p.ln1_s)[0] == 0x3F80);
  if (isbf) body<true>(p, sm);
  else      body<false>(p, sm);
}

extern "C" void kernel_launch(void* const* d_in, const int* in_sizes, int n_in,
                              void* d_out, int out_size, void* d_ws, size_t ws_size,
                              hipStream_t stream) {
  (void)in_sizes; (void)n_in; (void)out_size; (void)d_ws; (void)ws_size;
  Params p;
  p.x           = d_in[0];
  p.mask        = d_in[1];
  p.kp_w        = d_in[2];
  p.kp_b        = d_in[3];
  p.view_tokens = d_in[4];
  p.view_pos    = d_in[5];
  p.ln1_s       = d_in[6];
  p.ln1_b       = d_in[7];
  p.qkv_w       = d_in[8];
  p.qkv_b       = d_in[9];
  p.ap_w        = d_in[10];
  p.ap_b        = d_in[11];
  p.ln2_s       = d_in[12];
  p.ln2_b       = d_in[13];
  p.fc1_w       = d_in[14];
  p.fc1_b       = d_in[15];
  p.fc2_w       = d_in[16];
  p.fc2_b       = d_in[17];
  p.pool_probe  = d_in[18];
  p.pool_ln1_s  = d_in[19];
  p.pool_ln1_b  = d_in[20];
  p.pool_q_w    = d_in[21];
  p.pool_q_b    = d_in[22];
  p.pool_kv_w   = d_in[23];
  p.pool_kv_b   = d_in[24];
  p.pool_ap_w   = d_in[25];
  p.pool_ap_b   = d_in[26];
  p.pool_ln2_s  = d_in[27];
  p.pool_ln2_b  = d_in[28];
  p.pool_fc1_w  = d_in[29];
  p.pool_fc1_b  = d_in[30];
  p.pool_fc2_w  = d_in[31];
  p.pool_fc2_b  = d_in[32];
  p.pool_out_w  = d_in[33];
  p.pool_out_b  = d_in[34];
  p.last_s      = d_in[35];
  p.last_b      = d_in[36];
  p.out         = (float*)d_out;
  st_encoder_kernel<<<dim3(NS), dim3(NT), 0, stream>>>(p);
}

// Round 9
// 15107.809 us; speedup vs baseline: 6.2570x; 1.0769x over previous
//
#include <hip/hip_runtime.h>
#include <hip/hip_bf16.h>
#include <math.h>

// ---------------------------------------------------------------------------
// SpatialTransformerEncoder — round 9: MFMA GEMMs (split-bf16, fp32 accum).
// One 1024-thread block (16 waves) per sample. QKV/AP/FC1/FC2/pool-KV run on
// v_mfma_f32_16x16x32_bf16 with A = hi+lo bf16 (LN/attention outputs), B =
// hi+lo bf16 (weights converted inline from fp32 global; raw if bf16 global).
// M=17 padded to 32 (pad rows zeroed once). LN / attention / pool tail keep
// the r8-verified VALU path. FP32 output.
// ---------------------------------------------------------------------------

#define NB   2048
#define NC   3
#define NN   32
#define NE   256
#define NH   8
#define HDIM 32
#define NL   3
#define NMLP 1024
#define NP   256
#define NK   17        // 16 visible keypoints + view token
#define NS   (NB*NC)   // 6144
#define NT   1024      // threads per block
#define NW   16        // waves per block
#define AST  264       // A/H buffer row stride in bf16 elems (pad: 2-way-free banks)

typedef unsigned short u16;
typedef __attribute__((ext_vector_type(8))) short short8;   // 8 bf16 = 4 VGPRs
typedef __attribute__((ext_vector_type(4))) float float4v;  // MFMA C/D

struct Params {
  const void* x; const void* mask;
  const void* kp_w; const void* kp_b;
  const void* view_tokens; const void* view_pos;
  const void* ln1_s; const void* ln1_b;
  const void* qkv_w; const void* qkv_b;
  const void* ap_w; const void* ap_b;
  const void* ln2_s; const void* ln2_b;
  const void* fc1_w; const void* fc1_b;
  const void* fc2_w; const void* fc2_b;
  const void* pool_probe;
  const void* pool_ln1_s; const void* pool_ln1_b;
  const void* pool_q_w; const void* pool_q_b;
  const void* pool_kv_w; const void* pool_kv_b;
  const void* pool_ap_w; const void* pool_ap_b;
  const void* pool_ln2_s; const void* pool_ln2_b;
  const void* pool_fc1_w; const void* pool_fc1_b;
  const void* pool_fc2_w; const void* pool_fc2_b;
  const void* pool_out_w; const void* pool_out_b;
  const void* last_s; const void* last_b;
  float* out;
};

__device__ __forceinline__ float b2f(u16 u) {
  return __uint_as_float(((unsigned)u) << 16);
}
__device__ __forceinline__ u16 cvt16(float v) {   // fp32 -> bf16 bits (RNE)
  return __bfloat16_as_ushort(__float2bfloat16(v));
}
__device__ __forceinline__ float geluf(float v) {
  return 0.5f * v * (1.0f + erff(v * 0.70710678118654752f)); // exact GELU
}
template <bool BF>
__device__ __forceinline__ float LD(const void* q, int i) {
  if constexpr (BF) return b2f(((const u16*)q)[i]);
  else return ((const float*)q)[i];
}
__device__ __forceinline__ float4v vzero() {
  float4v z; z[0] = 0.f; z[1] = 0.f; z[2] = 0.f; z[3] = 0.f; return z;
}

struct alignas(16) Smem {
  float X[NK][NE];      // residual stream (fp32)
  float U[NK][768];     // QKV out / pool KV out (fp32)
  float Q[NE];          // pool q / normalized-y row
  float O[NE];          // pool attn-out row
  float RowA[NE];       // pool y / y2 row
  float Hh[NMLP];       // pool MLP hidden (fp32)
  float Pp[NH][NK];     // pool attn probs
  float Red[NW];
  u16 Ahi[32 * AST];    // GEMM A operand hi (LN out / attn context), 32 rows
  u16 Alo[32 * AST];    //               lo
  u16 Hhi[32 * AST];    // FC hidden chunk hi
  u16 Hlo[32 * AST];    //                 lo
  int Idx[NK];
};

// ---- LayerNorm over 17 rows of X -> hi/lo bf16 A-buffers ----
template <bool BF>
__device__ __forceinline__ void ln_hl(const float* __restrict__ In,
                                      u16* __restrict__ Oh, u16* __restrict__ Ol,
                                      const void* __restrict__ gam,
                                      const void* __restrict__ bet) {
  const int lane = threadIdx.x & 63, w = threadIdx.x >> 6;
  for (int t = w; t < NK; t += NW) {
    const float* row = In + t * NE;
    float sum = 0.f, sq = 0.f;
#pragma unroll
    for (int kk = 0; kk < NE / 64; ++kk) {
      const float v = row[lane + 64 * kk];
      sum += v; sq += v * v;
    }
#pragma unroll
    for (int off = 32; off > 0; off >>= 1) {
      sum += __shfl_down(sum, off, 64);
      sq  += __shfl_down(sq,  off, 64);
    }
    sum = __shfl(sum, 0, 64);
    sq  = __shfl(sq,  0, 64);
    const float mu = sum * (1.0f / NE);
    const float r  = rsqrtf(sq * (1.0f / NE) - mu * mu + 1e-5f);
#pragma unroll
    for (int kk = 0; kk < NE / 64; ++kk) {
      const int k = lane + 64 * kk;
      const float v = (row[k] - mu) * r * LD<BF>(gam, k) + LD<BF>(bet, k);
      const u16 hv = cvt16(v);
      Oh[t * AST + k] = hv;
      Ol[t * AST + k] = cvt16(v - b2f(hv));
    }
  }
}

// ---- MFMA core: wave w computes JOBS N-tiles (nt = w + jj*16) over K=256.
//      A: hi/lo bf16 LDS (32 rows, stride AST). W: global row-major (wN cols),
//      fp32 (split hi/lo inline) or bf16 (exact). D accumulates (caller init).
template <bool BF, int JOBS>
__device__ __forceinline__ void mfma_acc(const u16* __restrict__ Ah,
                                         const u16* __restrict__ Al,
                                         const void* __restrict__ W, const int wN,
                                         float4v D[JOBS][2]) {
  const int lane = threadIdx.x & 63, w = threadIdx.x >> 6;
  const int col = lane & 15, quad = lane >> 4;
  for (int ks = 0; ks < 8; ++ks) {
    const int k0 = ks * 32 + quad * 8;
    short8 ah[2], al[2];
#pragma unroll
    for (int mt = 0; mt < 2; ++mt) {
      const int m = mt * 16 + col;          // A row (lane&15 carries m)
      ah[mt] = *(const short8*)(Ah + m * AST + k0);
      al[mt] = *(const short8*)(Al + m * AST + k0);
    }
#pragma unroll
    for (int jj = 0; jj < JOBS; ++jj) {
      const int n = (w + jj * NW) * 16 + col;
      short8 bh, bl;
#pragma unroll
      for (int j2 = 0; j2 < 8; ++j2) {
        const size_t off = (size_t)(k0 + j2) * wN + n;
        if constexpr (BF) {
          bh[j2] = (short)((const u16*)W)[off];
        } else {
          const float wv = ((const float*)W)[off];
          const u16 hv = cvt16(wv);
          bh[j2] = (short)hv;
          bl[j2] = (short)cvt16(wv - b2f(hv));
        }
      }
#pragma unroll
      for (int mt = 0; mt < 2; ++mt) {
        D[jj][mt] = __builtin_amdgcn_mfma_f32_16x16x32_bf16(ah[mt], bh, D[jj][mt], 0, 0, 0);
        D[jj][mt] = __builtin_amdgcn_mfma_f32_16x16x32_bf16(al[mt], bh, D[jj][mt], 0, 0, 0);
        if constexpr (!BF)
          D[jj][mt] = __builtin_amdgcn_mfma_f32_16x16x32_bf16(ah[mt], bl, D[jj][mt], 0, 0, 0);
      }
    }
  }
}

// ---- block-wide sum over 1024 threads ----
__device__ __forceinline__ float block_sum(float v, float* sRed) {
#pragma unroll
  for (int off = 32; off > 0; off >>= 1) v += __shfl_down(v, off, 64);
  __syncthreads();
  if ((threadIdx.x & 63) == 0) sRed[threadIdx.x >> 6] = v;
  __syncthreads();
  float s = 0.f;
#pragma unroll
  for (int i = 0; i < NW; ++i) s += sRed[i];
  return s;
}

template <bool BF>
__device__ void body(const Params& p, Smem& sm) {
  const int s   = blockIdx.x;
  const int c   = s % NC;
  const int tid = threadIdx.x;
  const size_t EB = BF ? 2 : 4;
  const int lane = tid & 63, wv_ = tid >> 6, col = lane & 15, quad = lane >> 4;

  // ---- 0. zero bf16 operand buffers (pad rows must be 0) ----
  for (int i = tid; i < 32 * AST; i += NT) {
    sm.Ahi[i] = 0; sm.Alo[i] = 0; sm.Hhi[i] = 0; sm.Hlo[i] = 0;
  }

  // ---- 1. visibility gather (layout probe verified r3-r8) ----
  if (tid == 0) {
    const unsigned int* mw = (const unsigned int*)p.mask;
    bool byte_layout = false;
    for (int i = 0; i < 8; ++i) {
      const unsigned int w = mw[i];
      if (w != 0u && w != 1u && w != 0x3F800000u) { byte_layout = true; break; }
    }
    int np_ = 0;
    sm.Idx[np_++] = -1;
    if (byte_layout) {
      const unsigned char* mb = (const unsigned char*)p.mask;
      for (int n = 0; n < NN && np_ < NK; ++n)
        if (mb[(size_t)s * NN + n]) sm.Idx[np_++] = n;
    } else {
      for (int n = 0; n < NN && np_ < NK; ++n)
        if (mw[(size_t)s * NN + n] != 0u) sm.Idx[np_++] = n;
    }
    while (np_ < NK) sm.Idx[np_++] = 0;
  }
  __syncthreads();

  // ---- 2. embedding (4 thread-quarters over t) ----
  {
    const int e = tid & 255, q = tid >> 8;
    const float kw0 = LD<BF>(p.kp_w, e);
    const float kw1 = LD<BF>(p.kp_w, NE + e);
    const float kb  = LD<BF>(p.kp_b, e);
    const int   i2  = e & ~1;
    const float freq = expf(-((float)i2 / (float)NE) * logf(10000.0f));
    const float vt = LD<BF>(p.view_tokens, c * NE + e) + LD<BF>(p.view_pos, c * NE + e);
    for (int t = q; t < NK; t += 4) {
      const int n = sm.Idx[t];
      float v;
      if (n < 0) {
        v = vt;
      } else {
        const float x0 = LD<BF>(p.x, (s * NN + n) * 2 + 0);
        const float x1 = LD<BF>(p.x, (s * NN + n) * 2 + 1);
        const float ang = (float)n * freq;
        const float pe  = (e & 1) ? cosf(ang) : sinf(ang);
        v = x0 * kw0 + x1 * kw1 + kb + pe;
      }
      sm.X[t][e] = v;
    }
  }
  __syncthreads();

  // ---- 3. transformer blocks ----
  for (int l = 0; l < NL; ++l) {
    const void* qkvw = (const char*)p.qkv_w + (size_t)l * NE * 3 * NE * EB;
    const void* qkvb = (const char*)p.qkv_b + (size_t)l * 3 * NE * EB;
    const void* apw  = (const char*)p.ap_w  + (size_t)l * NE * NE * EB;
    const void* apb  = (const char*)p.ap_b  + (size_t)l * NE * EB;
    const void* f1b  = (const char*)p.fc1_b + (size_t)l * NMLP * EB;
    const void* f2bb = (const char*)p.fc2_b + (size_t)l * NE * EB;

    // LN1 -> A
    ln_hl<BF>(&sm.X[0][0], sm.Ahi, sm.Alo,
              (const char*)p.ln1_s + (size_t)l * NE * EB,
              (const char*)p.ln1_b + (size_t)l * NE * EB);
    __syncthreads();

    // QKV: N=768, 3 N-tiles per wave -> U fp32
    {
      float4v D[3][2];
#pragma unroll
      for (int a = 0; a < 3; ++a) { D[a][0] = vzero(); D[a][1] = vzero(); }
      mfma_acc<BF, 3>(sm.Ahi, sm.Alo, qkvw, 3 * NE, D);
#pragma unroll
      for (int jj = 0; jj < 3; ++jj) {
        const int n = (wv_ + jj * NW) * 16 + col;
        const float bb = LD<BF>(qkvb, n);
#pragma unroll
        for (int mt = 0; mt < 2; ++mt)
#pragma unroll
          for (int r = 0; r < 4; ++r) {
            const int m = mt * 16 + quad * 4 + r;
            if (m < NK) sm.U[m][n] = D[jj][mt][r] + bb;
          }
      }
    }
    __syncthreads();

    // attention (VALU, verified): reads U, writes context hi/lo into A
    if (tid < NH * NK) {
      const int h = tid / NK, t = tid % NK;
      const float* qr = &sm.U[t][h * HDIM];
      float sc[NK];
      float mx = -1e30f;
#pragma unroll
      for (int u = 0; u < NK; ++u) {
        const float* kr = &sm.U[u][NE + h * HDIM];
        float d = 0.f;
        for (int i = 0; i < HDIM; ++i) d += qr[i] * kr[i];
        d *= 0.17677669529663687f;
        sc[u] = d;
        mx = fmaxf(mx, d);
      }
      float den = 0.f;
#pragma unroll
      for (int u = 0; u < NK; ++u) { sc[u] = __expf(sc[u] - mx); den += sc[u]; }
      const float inv = 1.0f / den;
      for (int i = 0; i < HDIM; ++i) {
        float o = 0.f;
#pragma unroll
        for (int u = 0; u < NK; ++u) o += sc[u] * sm.U[u][2 * NE + h * HDIM + i];
        o *= inv;
        const int jc = h * HDIM + i;
        const u16 hv = cvt16(o);
        sm.Ahi[t * AST + jc] = hv;
        sm.Alo[t * AST + jc] = cvt16(o - b2f(hv));
      }
    }
    __syncthreads();

    // proj + residual: X += A @ ap_w + ap_b (N=256, 1 tile/wave)
    {
      float4v D[1][2];
      D[0][0] = vzero(); D[0][1] = vzero();
      mfma_acc<BF, 1>(sm.Ahi, sm.Alo, apw, NE, D);
      const int n = wv_ * 16 + col;
      const float bb = LD<BF>(apb, n);
#pragma unroll
      for (int mt = 0; mt < 2; ++mt)
#pragma unroll
        for (int r = 0; r < 4; ++r) {
          const int m = mt * 16 + quad * 4 + r;
          if (m < NK) sm.X[m][n] = sm.X[m][n] + D[0][mt][r] + bb;
        }
    }
    __syncthreads();

    // LN2 -> A
    ln_hl<BF>(&sm.X[0][0], sm.Ahi, sm.Alo,
              (const char*)p.ln2_s + (size_t)l * NE * EB,
              (const char*)p.ln2_b + (size_t)l * NE * EB);
    __syncthreads();

    // FC1 (+GELU) -> H chunks of 256; FC2 accumulates over chunks -> X
    {
      float4v D2[1][2];
      D2[0][0] = vzero(); D2[0][1] = vzero();
      for (int chunk = 0; chunk < 4; ++chunk) {
        {
          float4v D1[1][2];
          D1[0][0] = vzero(); D1[0][1] = vzero();
          const void* f1w = (const char*)p.fc1_w +
              ((size_t)l * NE * NMLP + (size_t)chunk * 256) * EB;
          mfma_acc<BF, 1>(sm.Ahi, sm.Alo, f1w, NMLP, D1);
          const int n = wv_ * 16 + col;
          const float bb = LD<BF>(f1b, chunk * 256 + n);
#pragma unroll
          for (int mt = 0; mt < 2; ++mt)
#pragma unroll
            for (int r = 0; r < 4; ++r) {
              const int m = mt * 16 + quad * 4 + r;
              if (m < NK) {
                const float v = geluf(D1[0][mt][r] + bb);
                const u16 hv = cvt16(v);
                sm.Hhi[m * AST + n] = hv;
                sm.Hlo[m * AST + n] = cvt16(v - b2f(hv));
              }
            }
        }
        __syncthreads();
        const void* f2w = (const char*)p.fc2_w +
            ((size_t)l * NMLP * NE + (size_t)chunk * 256 * NE) * EB;
        mfma_acc<BF, 1>(sm.Hhi, sm.Hlo, f2w, NE, D2);
        __syncthreads();
      }
      const int n = wv_ * 16 + col;
      const float bb = LD<BF>(f2bb, n);
#pragma unroll
      for (int mt = 0; mt < 2; ++mt)
#pragma unroll
        for (int r = 0; r < 4; ++r) {
          const int m = mt * 16 + quad * 4 + r;
          if (m < NK) sm.X[m][n] = sm.X[m][n] + D2[0][mt][r] + bb;
        }
    }
    __syncthreads();
  }

  // ---- 4. attention pooling ----
  ln_hl<BF>(&sm.X[0][0], sm.Ahi, sm.Alo, p.pool_ln1_s, p.pool_ln1_b);
  __syncthreads();
  // q row from probe (VALU, independent)
  if (tid < NE) {
    const int j = tid;
    float a = LD<BF>(p.pool_q_b, j);
    for (int k = 0; k < NE; k += 4) {
      a += LD<BF>(p.pool_probe, k + 0) * LD<BF>(p.pool_q_w, (k + 0) * NE + j) +
           LD<BF>(p.pool_probe, k + 1) * LD<BF>(p.pool_q_w, (k + 1) * NE + j) +
           LD<BF>(p.pool_probe, k + 2) * LD<BF>(p.pool_q_w, (k + 2) * NE + j) +
           LD<BF>(p.pool_probe, k + 3) * LD<BF>(p.pool_q_w, (k + 3) * NE + j);
    }
    sm.Q[j] = a;
  }
  // pool KV: N=512, 2 tiles/wave -> U fp32
  {
    float4v D[2][2];
#pragma unroll
    for (int a = 0; a < 2; ++a) { D[a][0] = vzero(); D[a][1] = vzero(); }
    mfma_acc<BF, 2>(sm.Ahi, sm.Alo, p.pool_kv_w, 2 * NE, D);
#pragma unroll
    for (int jj = 0; jj < 2; ++jj) {
      const int n = (wv_ + jj * NW) * 16 + col;
      const float bb = LD<BF>(p.pool_kv_b, n);
#pragma unroll
      for (int mt = 0; mt < 2; ++mt)
#pragma unroll
        for (int r = 0; r < 4; ++r) {
          const int m = mt * 16 + quad * 4 + r;
          if (m < NK) sm.U[m][n] = D[jj][mt][r] + bb;
        }
    }
  }
  __syncthreads();
  // scores + softmax per head
  if (tid < NH) {
    const int h = tid;
    float sc[NK];
    float mx = -1e30f;
#pragma unroll
    for (int u = 0; u < NK; ++u) {
      float d = 0.f;
      for (int i = 0; i < HDIM; ++i) d += sm.Q[h * HDIM + i] * sm.U[u][h * HDIM + i];
      d *= 0.17677669529663687f;
      sc[u] = d;
      mx = fmaxf(mx, d);
    }
    float den = 0.f;
#pragma unroll
    for (int u = 0; u < NK; ++u) { sc[u] = __expf(sc[u] - mx); den += sc[u]; }
    const float inv = 1.0f / den;
#pragma unroll
    for (int u = 0; u < NK; ++u) sm.Pp[h][u] = sc[u] * inv;
  }
  __syncthreads();
  // o row
  if (tid < NE) {
    const int j = tid, h = j >> 5, i = j & 31;
    float o = 0.f;
#pragma unroll
    for (int u = 0; u < NK; ++u) o += sm.Pp[h][u] * sm.U[u][NE + h * HDIM + i];
    sm.O[j] = o;
  }
  __syncthreads();
  // y = probe + o @ ap_w + ap_b
  float yv = 0.f;
  if (tid < NE) {
    const int j = tid;
    float a = LD<BF>(p.pool_ap_b, j);
    for (int k = 0; k < NE; k += 4) {
      const float4 oo = *(const float4*)&sm.O[k];
      a += oo.x * LD<BF>(p.pool_ap_w, (k + 0) * NE + j) +
           oo.y * LD<BF>(p.pool_ap_w, (k + 1) * NE + j) +
           oo.z * LD<BF>(p.pool_ap_w, (k + 2) * NE + j) +
           oo.w * LD<BF>(p.pool_ap_w, (k + 3) * NE + j);
    }
    yv = LD<BF>(p.pool_probe, j) + a;
  }
  // LN(y) -> Q
  {
    const float s1 = block_sum(yv, sm.Red);
    const float s2 = block_sum(yv * yv, sm.Red);
    const float mu = s1 * (1.0f / NE);
    const float r  = rsqrtf(s2 * (1.0f / NE) - mu * mu + 1e-5f);
    if (tid < NE)
      sm.Q[tid] = (yv - mu) * r * LD<BF>(p.pool_ln2_s, tid) + LD<BF>(p.pool_ln2_b, tid);
  }
  __syncthreads();
  // pool MLP hidden (1 output/thread)
  {
    const int j = tid;
    float a = LD<BF>(p.pool_fc1_b, j);
    for (int k = 0; k < NE; k += 4) {
      const float4 nq = *(const float4*)&sm.Q[k];
      a += nq.x * LD<BF>(p.pool_fc1_w, (k + 0) * NMLP + j) +
           nq.y * LD<BF>(p.pool_fc1_w, (k + 1) * NMLP + j) +
           nq.z * LD<BF>(p.pool_fc1_w, (k + 2) * NMLP + j) +
           nq.w * LD<BF>(p.pool_fc1_w, (k + 3) * NMLP + j);
    }
    sm.Hh[j] = geluf(a);
  }
  __syncthreads();
  // y2 = y + Hh @ fc2 + b
  if (tid < NE) {
    const int j = tid;
    float a = LD<BF>(p.pool_fc2_b, j);
    for (int k = 0; k < NMLP; k += 4) {
      const float4 hh = *(const float4*)&sm.Hh[k];
      a += hh.x * LD<BF>(p.pool_fc2_w, (k + 0) * NE + j) +
           hh.y * LD<BF>(p.pool_fc2_w, (k + 1) * NE + j) +
           hh.z * LD<BF>(p.pool_fc2_w, (k + 2) * NE + j) +
           hh.w * LD<BF>(p.pool_fc2_w, (k + 3) * NE + j);
    }
    sm.RowA[j] = yv + a;
  }
  __syncthreads();
  // out = y2 @ out_w + out_b ; final LN
  float ov = 0.f;
  if (tid < NP) {
    const int j = tid;
    float a = LD<BF>(p.pool_out_b, j);
    for (int k = 0; k < NE; k += 4) {
      const float4 yy = *(const float4*)&sm.RowA[k];
      a += yy.x * LD<BF>(p.pool_out_w, (k + 0) * NP + j) +
           yy.y * LD<BF>(p.pool_out_w, (k + 1) * NP + j) +
           yy.z * LD<BF>(p.pool_out_w, (k + 2) * NP + j) +
           yy.w * LD<BF>(p.pool_out_w, (k + 3) * NP + j);
    }
    ov = a;
  }
  {
    const float s1 = block_sum(ov, sm.Red);
    const float s2 = block_sum(ov * ov, sm.Red);
    const float mu = s1 * (1.0f / NP);
    const float r  = rsqrtf(s2 * (1.0f / NP) - mu * mu + 1e-5f);
    if (tid < NP) {
      const float res = (ov - mu) * r * LD<BF>(p.last_s, tid) + LD<BF>(p.last_b, tid);
      p.out[(size_t)s * NP + tid] = res;
    }
  }
}

__global__ __launch_bounds__(NT, 1)
void st_encoder_kernel(Params p) {
  __shared__ Smem sm;
  const bool isbf = (((const u16*)p.ln1_s)[0] == 0x3F80);
  if (isbf) body<true>(p, sm);
  else      body<false>(p, sm);
}

extern "C" void kernel_launch(void* const* d_in, const int* in_sizes, int n_in,
                              void* d_out, int out_size, void* d_ws, size_t ws_size,
                              hipStream_t stream) {
  (void)in_sizes; (void)n_in; (void)out_size; (void)d_ws; (void)ws_size;
  Params p;
  p.x           = d_in[0];
  p.mask        = d_in[1];
  p.kp_w        = d_in[2];
  p.kp_b        = d_in[3];
  p.view_tokens = d_in[4];
  p.view_pos    = d_in[5];
  p.ln1_s       = d_in[6];
  p.ln1_b       = d_in[7];
  p.qkv_w       = d_in[8];
  p.qkv_b       = d_in[9];
  p.ap_w        = d_in[10];
  p.ap_b        = d_in[11];
  p.ln2_s       = d_in[12];
  p.ln2_b       = d_in[13];
  p.fc1_w       = d_in[14];
  p.fc1_b       = d_in[15];
  p.fc2_w       = d_in[16];
  p.fc2_b       = d_in[17];
  p.pool_probe  = d_in[18];
  p.pool_ln1_s  = d_in[19];
  p.pool_ln1_b  = d_in[20];
  p.pool_q_w    = d_in[21];
  p.pool_q_b    = d_in[22];
  p.pool_kv_w   = d_in[23];
  p.pool_kv_b   = d_in[24];
  p.pool_ap_w   = d_in[25];
  p.pool_ap_b   = d_in[26];
  p.pool_ln2_s  = d_in[27];
  p.pool_ln2_b  = d_in[28];
  p.pool_fc1_w  = d_in[29];
  p.pool_fc1_b  = d_in[30];
  p.pool_fc2_w  = d_in[31];
  p.pool_fc2_b  = d_in[32];
  p.pool_out_w  = d_in[33];
  p.pool_out_b  = d_in[34];
  p.last_s      = d_in[35];
  p.last_b      = d_in[36];
  p.out         = (float*)d_out;
  st_encoder_kernel<<<dim3(NS), dim3(NT), 0, stream>>>(p);
}